// Round 7
// baseline (334.171 us; speedup 1.0000x reference)
//
#include <hip/hip_runtime.h>
#include <stdint.h>
#include <stddef.h>

// Problem constants
#define B_   8
#define N_   8192
#define S_   2048
#define D_   256
#define M_   (B_*N_)     // 65536 total points
#define C0_  256         // MLP[0]
#define C1_  128         // MLP[1]
#define K2D_ 512         // 2*D
#define TS8_ 8           // S-segments (waves) per topk block
#define SEG8_ (S_/TS8_)  // 256
#define SWP_ 264         // padded LDS row stride (shorts) for W1 in gemm2
#define SWC_ 268         // padded LDS row stride (shorts) for C staging in gemm1

typedef __attribute__((ext_vector_type(8))) short short8;
typedef __attribute__((ext_vector_type(4))) float f32x4;
typedef __attribute__((ext_vector_type(2))) float f32x2;

__device__ __forceinline__ short f2bf(float f) {
  unsigned u = __float_as_uint(f);
  u += 0x7fffu + ((u >> 16) & 1u);   // round-to-nearest-even
  return (short)(u >> 16);
}
__device__ __forceinline__ float bf2f(short s) {
  return __uint_as_float(((unsigned)(unsigned short)s) << 16);
}

__device__ __forceinline__ void cp16(const void* g, void* l) {
  __builtin_amdgcn_global_load_lds(
      (__attribute__((address_space(1))) void*)(g),
      (__attribute__((address_space(3))) void*)(l), 16, 0, 0);
}

// ---------------------------------------------------------------------------
// K0: convert W0/W1 to bf16; build component-SoA xyz2p; zero stats buffer.
// ---------------------------------------------------------------------------
__global__ void convw_kernel(const float* __restrict__ W0,
                             const float* __restrict__ W1,
                             const float* __restrict__ xyz2,
                             short* __restrict__ W0b, short* __restrict__ W1b,
                             float* __restrict__ xyz2p, float* __restrict__ stats) {
  int i = blockIdx.x * 256 + threadIdx.x;
  if (blockIdx.x == 0) {
    stats[threadIdx.x] = 0.f;
    stats[256 + threadIdx.x] = 0.f;
    stats[512 + threadIdx.x] = 0.f;
  }
  if (i < C0_ * K2D_) W0b[i] = f2bf(W0[i]);
  if (i < C1_ * C0_)  W1b[i] = f2bf(W1[i]);
  if (i < B_ * S_) {
    const int b = i >> 11, s = i & (S_ - 1);
    float x = xyz2[(size_t)i * 3 + 0];
    float y = xyz2[(size_t)i * 3 + 1];
    float z = xyz2[(size_t)i * 3 + 2];
    float ss = __fadd_rn(__fadd_rn(__fmul_rn(x, x), __fmul_rn(y, y)), __fmul_rn(z, z));
    float* xw = xyz2p + (size_t)b * 4 * S_;
    xw[s] = x; xw[S_ + s] = y; xw[2 * S_ + s] = z; xw[3 * S_ + s] = ss;
  }
}

// ---------------------------------------------------------------------------
// K1: top-3 NN + sigmoid relation weights (unchanged from R5).
// ---------------------------------------------------------------------------
__global__ __launch_bounds__(512, 8)
void topk_kernel(const float* __restrict__ xyz1, const float* __restrict__ xyz2p,
                 const float* __restrict__ relw, const float* __restrict__ relb,
                 int* __restrict__ idx_out, float* __restrict__ w_out) {
  __shared__ float cd[TS8_][64][3];
  __shared__ int   ci[TS8_][64][3];
  const int tid  = threadIdx.x;
  const int lane = tid & 63;
  const int seg  = __builtin_amdgcn_readfirstlane(tid >> 6);
  const int b    = blockIdx.x >> 7;
  const int n    = (blockIdx.x & 127) * 64 + lane;

  const float* p = xyz1 + ((size_t)b * N_ + n) * 3;
  const float ax = p[0], ay = p[1], az = p[2];
  const float s1 = __fadd_rn(__fadd_rn(__fmul_rn(ax, ax), __fmul_rn(ay, ay)), __fmul_rn(az, az));

  const float* xw = xyz2p + (size_t)b * 4 * S_;
  const f32x2* XP = (const f32x2*)(xw)           + seg * (SEG8_ / 2);
  const f32x2* YP = (const f32x2*)(xw + S_)      + seg * (SEG8_ / 2);
  const f32x2* ZP = (const f32x2*)(xw + 2 * S_)  + seg * (SEG8_ / 2);
  const f32x2* WP = (const f32x2*)(xw + 3 * S_)  + seg * (SEG8_ / 2);

  float d0 = 3.4e38f, d1 = 3.4e38f, d2 = 3.4e38f;
  int   i0 = 0, i1 = 0, i2 = 0;
  const int sbeg = seg * SEG8_;
  {
    #pragma clang fp contract(off)
    #pragma unroll 4
    for (int pr = 0; pr < SEG8_ / 2; pr++) {
      f32x2 X = XP[pr], Y = YP[pr], Z = ZP[pr], W = WP[pr];
      f32x2 t1 = ax * X;
      f32x2 t2 = ay * Y;
      f32x2 t3 = az * Z;
      f32x2 dt = (t1 + t2) + t3;
      f32x2 e  = s1 + W;
      f32x2 m  = 2.0f * dt;
      f32x2 d  = e - m;
      const float dlo = d.x, dhi = d.y;
      if (fminf(dlo, dhi) < d2) {
        const int s = sbeg + 2 * pr;
        if (dlo < d2) {
          if (dlo < d1) {
            d2 = d1; i2 = i1;
            if (dlo < d0) { d1 = d0; i1 = i0; d0 = dlo; i0 = s; }
            else          { d1 = dlo; i1 = s; }
          } else { d2 = dlo; i2 = s; }
        }
        if (dhi < d2) {
          if (dhi < d1) {
            d2 = d1; i2 = i1;
            if (dhi < d0) { d1 = d0; i1 = i0; d0 = dhi; i0 = s + 1; }
            else          { d1 = dhi; i1 = s + 1; }
          } else { d2 = dhi; i2 = s + 1; }
        }
      }
    }
  }
  cd[seg][lane][0] = d0; cd[seg][lane][1] = d1; cd[seg][lane][2] = d2;
  ci[seg][lane][0] = i0; ci[seg][lane][1] = i1; ci[seg][lane][2] = i2;
  __syncthreads();

  if (tid < 64) {
    float m0 = 3.4e38f, m1 = 3.4e38f, m2 = 3.4e38f;
    int   j0 = 0, j1 = 0, j2 = 0;
    #pragma unroll
    for (int sg = 0; sg < TS8_; sg++) {
      #pragma unroll
      for (int k = 0; k < 3; k++) {
        float d = cd[sg][tid][k];
        int   ix = ci[sg][tid][k];
        if (d < m2) {
          if (d < m1) {
            m2 = m1; j2 = j1;
            if (d < m0) { m1 = m0; j1 = j0; m0 = d; j0 = ix; }
            else        { m1 = d;  j1 = ix; }
          } else { m2 = d; j2 = ix; }
        }
      }
    }
    const float w0r = relw[0], w1r = relw[1], w2r = relw[2], w3r = relw[3], br = relb[0];
    const size_t base = ((size_t)b * N_ + n) * 3;
    float dd[3] = {m0, m1, m2};
    int   ii[3] = {j0, j1, j2};
    #pragma unroll
    for (int k = 0; k < 3; k++) {
      const int s = ii[k];
      float ox = ax - xw[s], oy = ay - xw[S_ + s], oz = az - xw[2 * S_ + s];
      float t = dd[k] * w0r + ox * w1r + oy * w2r + oz * w3r + br;
      float w = 1.0f / (1.0f + expf(-t));
      idx_out[base + k] = s;
      w_out[base + k] = w * (1.0f / 3.0f);
    }
  }
}

// ---------------------------------------------------------------------------
// GEMM1 (fused build_h): a1[M][256](bf16) = h @ W0^T.
// BARRIER-FREE K-loop: B-fragments loaded per-lane directly from global
// (W0b = 256 KB, read by all 512 blocks -> L1/L2-resident); A-fragments built
// in registers (p1 pass-through or 3-way p2 gather+combine), raw data
// prefetched one K-step ahead. Block = 4 waves x 32 rows = 128 rows x N=256.
// acc: 2 m-frags x 16 n-frags. Epilogue: C staged through padded LDS for
// coalesced 16B stores + per-column (sum,sumsq) atomics (bias excluded).
// ---------------------------------------------------------------------------
__global__ __launch_bounds__(256, 2)
void gemm1_kernel(const float* __restrict__ p1, const float* __restrict__ p2,
                  const int* __restrict__ idx, const float* __restrict__ wts,
                  const short* __restrict__ Bw, const float* __restrict__ bias,
                  short* __restrict__ Cb, float* __restrict__ stats) {
  __shared__ __align__(16) short sC[128 * SWC_];   // 68.6 KB C staging
  __shared__ float sred[3][2][C0_];                // 6 KB cross-wave stats
  const int tid  = threadIdx.x;
  const int lane = tid & 63;
  const int wave = tid >> 6;
  const int mr = lane & 15;
  const int kq = (lane >> 4) * 8;      // 0,8,16,24
  const int r0 = blockIdx.x * 128 + wave * 32;

  // per-lane row metadata for the 2 m-frags
  int rowg[2]; int ia[2][3]; float wa[2][3]; const float* pbase[2];
  #pragma unroll
  for (int t = 0; t < 2; t++) {
    const int row = r0 + t * 16 + mr;
    rowg[t] = row;
    pbase[t] = p2 + (size_t)(row >> 13) * S_ * D_;
    ia[t][0] = idx[row * 3 + 0]; ia[t][1] = idx[row * 3 + 1]; ia[t][2] = idx[row * 3 + 2];
    wa[t][0] = wts[row * 3 + 0]; wa[t][1] = wts[row * 3 + 1]; wa[t][2] = wts[row * 3 + 2];
  }

  f32x4 acc[2][16] = {};
  float4 ar[2][6];

  #define LOAD_A(K0)                                                          \
    if ((K0) < D_) {                                                          \
      _Pragma("unroll")                                                       \
      for (int t = 0; t < 2; t++) {                                           \
        const float* src = p1 + (size_t)rowg[t] * D_ + (K0) + kq;             \
        ar[t][0] = *(const float4*)src; ar[t][1] = *(const float4*)(src + 4); \
      }                                                                       \
    } else {                                                                  \
      const int c2 = (K0) - D_ + kq;                                          \
      _Pragma("unroll")                                                       \
      for (int t = 0; t < 2; t++) {                                           \
        const float* q0 = pbase[t] + (size_t)ia[t][0] * D_ + c2;              \
        const float* q1 = pbase[t] + (size_t)ia[t][1] * D_ + c2;              \
        const float* q2 = pbase[t] + (size_t)ia[t][2] * D_ + c2;              \
        ar[t][0] = *(const float4*)q0; ar[t][1] = *(const float4*)(q0 + 4);   \
        ar[t][2] = *(const float4*)q1; ar[t][3] = *(const float4*)(q1 + 4);   \
        ar[t][4] = *(const float4*)q2; ar[t][5] = *(const float4*)(q2 + 4);   \
      }                                                                       \
    }

  LOAD_A(0);

  #pragma unroll 1
  for (int k0 = 0; k0 < K2D_; k0 += 32) {
    // convert prefetched raw A -> bf16 fragments
    short8 af[2];
    if (k0 < D_) {
      #pragma unroll
      for (int t = 0; t < 2; t++) {
        float fv[8] = {ar[t][0].x, ar[t][0].y, ar[t][0].z, ar[t][0].w,
                       ar[t][1].x, ar[t][1].y, ar[t][1].z, ar[t][1].w};
        short8 o;
        #pragma unroll
        for (int e = 0; e < 8; e++) o[e] = f2bf(fv[e]);
        af[t] = o;
      }
    } else {
      #pragma unroll
      for (int t = 0; t < 2; t++) {
        float fv[8];
        fv[0] = wa[t][0] * ar[t][0].x + wa[t][1] * ar[t][2].x + wa[t][2] * ar[t][4].x;
        fv[1] = wa[t][0] * ar[t][0].y + wa[t][1] * ar[t][2].y + wa[t][2] * ar[t][4].y;
        fv[2] = wa[t][0] * ar[t][0].z + wa[t][1] * ar[t][2].z + wa[t][2] * ar[t][4].z;
        fv[3] = wa[t][0] * ar[t][0].w + wa[t][1] * ar[t][2].w + wa[t][2] * ar[t][4].w;
        fv[4] = wa[t][0] * ar[t][1].x + wa[t][1] * ar[t][3].x + wa[t][2] * ar[t][5].x;
        fv[5] = wa[t][0] * ar[t][1].y + wa[t][1] * ar[t][3].y + wa[t][2] * ar[t][5].y;
        fv[6] = wa[t][0] * ar[t][1].z + wa[t][1] * ar[t][3].z + wa[t][2] * ar[t][5].z;
        fv[7] = wa[t][0] * ar[t][1].w + wa[t][1] * ar[t][3].w + wa[t][2] * ar[t][5].w;
        short8 o;
        #pragma unroll
        for (int e = 0; e < 8; e++) o[e] = f2bf(fv[e]);
        af[t] = o;
      }
    }
    // prefetch next K-step's raw A (in flight across the MFMA burst)
    const int kn = k0 + 32;
    if (kn < K2D_) { LOAD_A(kn); }

    // B-frags straight from global (L1/L2-hot) + MFMA burst
    #pragma unroll
    for (int j = 0; j < 16; j++) {
      short8 bf = *(const short8*)(Bw + (size_t)(j * 16 + mr) * K2D_ + k0 + kq);
      acc[0][j] = __builtin_amdgcn_mfma_f32_16x16x32_bf16(af[0], bf, acc[0][j], 0, 0, 0);
      acc[1][j] = __builtin_amdgcn_mfma_f32_16x16x32_bf16(af[1], bf, acc[1][j], 0, 0, 0);
    }
  }
  #undef LOAD_A

  // Epilogue
  const int cr = (lane >> 4) * 4;
  const int cc = lane & 15;
  float ps[16], ps2[16];
  #pragma unroll
  for (int j = 0; j < 16; j++) {
    const int col = j * 16 + cc;
    const float bv = bias[col];
    float s = 0.f, s2 = 0.f;
    #pragma unroll
    for (int t = 0; t < 2; t++) {
      #pragma unroll
      for (int r = 0; r < 4; r++) {
        const float v = acc[t][j][r];
        s += v; s2 += v * v;
        sC[(wave * 32 + t * 16 + cr + r) * SWC_ + col] = f2bf(v + bv);
      }
    }
    ps[j] = s; ps2[j] = s2;
  }
  #pragma unroll
  for (int j = 0; j < 16; j++) {
    ps[j]  += __shfl_xor(ps[j], 16);  ps[j]  += __shfl_xor(ps[j], 32);
    ps2[j] += __shfl_xor(ps2[j], 16); ps2[j] += __shfl_xor(ps2[j], 32);
  }
  if (wave > 0 && lane < 16) {
    #pragma unroll
    for (int j = 0; j < 16; j++) {
      const int c = j * 16 + lane;
      sred[wave - 1][0][c] = ps[j];
      sred[wave - 1][1][c] = ps2[j];
    }
  }
  __syncthreads();
  if (wave == 0 && lane < 16) {
    #pragma unroll
    for (int j = 0; j < 16; j++) {
      const int c = j * 16 + lane;
      atomicAdd(&stats[c],       ps[j]  + sred[0][0][c] + sred[1][0][c] + sred[2][0][c]);
      atomicAdd(&stats[C0_ + c], ps2[j] + sred[0][1][c] + sred[1][1][c] + sred[2][1][c]);
    }
  }
  // coalesced C store: 128 rows x 256 bf16 = 4096 chunks of 16B
  #pragma unroll
  for (int t2 = 0; t2 < 16; t2++) {
    const int flat = t2 * 256 + tid;
    const int rr = flat >> 5;
    const int ch = flat & 31;
    short8 vv = *(short8*)&sC[rr * SWC_ + ch * 8];
    *(short8*)(Cb + ((size_t)blockIdx.x * 128 + rr) * C0_ + ch * 8) = vv;
  }
}

// ---------------------------------------------------------------------------
// GEMM2 (fused norm1): a2[M][128](bf16) = relu(bn(a1)) @ W1^T. (unchanged)
// ---------------------------------------------------------------------------
__global__ __launch_bounds__(256, 2)
void gemm2_kernel(const short* __restrict__ A, const short* __restrict__ Bw,
                  const float* __restrict__ ssn, const float* __restrict__ bias,
                  short* __restrict__ Cb, float* __restrict__ stats) {
  __shared__ __align__(16) short sW[C1_ * SWP_];  // 128 x 264 shorts = 66 KB
  __shared__ float sred[3 * 256];
  const int tid = threadIdx.x;
  const int lane = tid & 63;
  const int wave = tid >> 6;
  const size_t mbase = (size_t)blockIdx.x * 128;

  #pragma unroll
  for (int i = 0; i < 16; i++) {
    const int flat = i * 256 + tid;
    const int n = flat >> 5;
    const int kb = flat & 31;
    *(short8*)&sW[n * SWP_ + kb * 8] = *(const short8*)(Bw + (size_t)flat * 8);
  }
  __syncthreads();

  f32x4 acc[2][8] = {};
  const int mr = lane & 15;
  const int ksq = (lane >> 4) * 8;

  for (int k0 = 0; k0 < C0_; k0 += 32) {
    const int kk = k0 + ksq;
    float4 sc0 = *(const float4*)(ssn + kk);
    float4 sc1 = *(const float4*)(ssn + kk + 4);
    float4 sh0 = *(const float4*)(ssn + C0_ + kk);
    float4 sh1 = *(const float4*)(ssn + C0_ + kk + 4);
    const float sc[8] = {sc0.x, sc0.y, sc0.z, sc0.w, sc1.x, sc1.y, sc1.z, sc1.w};
    const float sh[8] = {sh0.x, sh0.y, sh0.z, sh0.w, sh1.x, sh1.y, sh1.z, sh1.w};
    short8 af[2];
    #pragma unroll
    for (int i = 0; i < 2; i++) {
      const size_t row = mbase + wave * 32 + i * 16 + mr;
      short8 av = *(const short8*)(A + row * C0_ + kk);
      short8 o;
      #pragma unroll
      for (int e = 0; e < 8; e++) {
        float f = bf2f(av[e]) * sc[e] + sh[e];
        o[e] = f2bf(f > 0.f ? f : 0.f);
      }
      af[i] = o;
    }
    short8 bf8[8];
    #pragma unroll
    for (int j = 0; j < 8; j++) bf8[j] = *(const short8*)&sW[(j * 16 + mr) * SWP_ + kk];
    #pragma unroll
    for (int i = 0; i < 2; i++)
      #pragma unroll
      for (int j = 0; j < 8; j++)
        acc[i][j] = __builtin_amdgcn_mfma_f32_16x16x32_bf16(af[i], bf8[j], acc[i][j], 0, 0, 0);
  }

  const int cr = (lane >> 4) * 4;
  const int cc = lane & 15;
  float ps[8], ps2[8];
  #pragma unroll
  for (int j = 0; j < 8; j++) {
    const int col = j * 16 + cc;
    const float bv = bias[col];
    float s = 0.f, s2 = 0.f;
    #pragma unroll
    for (int i = 0; i < 2; i++) {
      #pragma unroll
      for (int r = 0; r < 4; r++) {
        const float vv = acc[i][j][r];
        s += vv; s2 += vv * vv;
        const size_t row = mbase + wave * 32 + i * 16 + cr + r;
        Cb[row * C1_ + col] = f2bf(vv + bv);
      }
    }
    ps[j] = s; ps2[j] = s2;
  }
  #pragma unroll
  for (int j = 0; j < 8; j++) {
    ps[j]  += __shfl_xor(ps[j], 16);  ps[j]  += __shfl_xor(ps[j], 32);
    ps2[j] += __shfl_xor(ps2[j], 16); ps2[j] += __shfl_xor(ps2[j], 32);
  }
  if (wave > 0 && lane < 16) {
    #pragma unroll
    for (int j = 0; j < 8; j++) {
      const int c = j * 16 + lane;
      sred[(wave - 1) * 256 + c]       = ps[j];
      sred[(wave - 1) * 256 + 128 + c] = ps2[j];
    }
  }
  __syncthreads();
  if (wave == 0 && lane < 16) {
    #pragma unroll
    for (int j = 0; j < 8; j++) {
      const int c = j * 16 + lane;
      float s  = ps[j]  + sred[c]       + sred[256 + c]       + sred[512 + c];
      float s2 = ps2[j] + sred[128 + c] + sred[256 + 128 + c] + sred[512 + 128 + c];
      atomicAdd(&stats[c],       s);
      atomicAdd(&stats[C1_ + c], s2);
    }
  }
}

// ---------------------------------------------------------------------------
// stats_final: scale/shift from accumulated (sum, sumsq); bias folded in.
// ---------------------------------------------------------------------------
__global__ void stats_final_kernel(const float* __restrict__ stats, const int C,
                                   const float* __restrict__ bias,
                                   const float* __restrict__ g, const float* __restrict__ be,
                                   float* __restrict__ ss) {
  const int c = threadIdx.x;
  if (c >= C) return;
  const float inv = 1.0f / (float)M_;
  float m0 = stats[c] * inv;
  float var = stats[C + c] * inv - m0 * m0;
  float mean = m0 + bias[c];
  float sc = g[c] * rsqrtf(var + 1e-5f);
  ss[c] = sc;
  ss[C + c] = be[c] - mean * sc;
}

// ---------------------------------------------------------------------------
// norm2: out(f32) = relu(a2*sc + sh), 8 elems/thread
// ---------------------------------------------------------------------------
__global__ __launch_bounds__(256, 1)
void norm2_kernel(const short* __restrict__ a2, const float* __restrict__ ss,
                  float* __restrict__ out) {
  const size_t t = (size_t)blockIdx.x * 256 + threadIdx.x;
  const size_t base = t * 8;
  const int c = (int)(base & (C1_ - 1));
  short8 v8 = *(const short8*)(a2 + base);
  float vv[8];
  #pragma unroll
  for (int k = 0; k < 8; k++) {
    float v = bf2f(v8[k]) * ss[c + k] + ss[C1_ + c + k];
    vv[k] = v > 0.f ? v : 0.f;
  }
  *(float4*)(out + base)     = make_float4(vv[0], vv[1], vv[2], vv[3]);
  *(float4*)(out + base + 4) = make_float4(vv[4], vv[5], vv[6], vv[7]);
}

// ---------------------------------------------------------------------------
// Launch
// ---------------------------------------------------------------------------
extern "C" void kernel_launch(void* const* d_in, const int* in_sizes, int n_in,
                              void* d_out, int out_size, void* d_ws, size_t ws_size,
                              hipStream_t stream) {
  const float* xyz1 = (const float*)d_in[0];
  const float* xyz2 = (const float*)d_in[1];
  const float* pts1 = (const float*)d_in[2];
  const float* pts2 = (const float*)d_in[3];
  const float* relw = (const float*)d_in[4];
  const float* relb = (const float*)d_in[5];
  const float* W0   = (const float*)d_in[6];
  const float* b0   = (const float*)d_in[7];
  const float* g0   = (const float*)d_in[8];
  const float* be0  = (const float*)d_in[9];
  const float* W1   = (const float*)d_in[10];
  const float* b1   = (const float*)d_in[11];
  const float* g1   = (const float*)d_in[12];
  const float* be1  = (const float*)d_in[13];

  char* ws = (char*)d_ws;
  constexpr size_t IDX_OFF = 0;                                    // M*3 int
  constexpr size_t WTS_OFF = IDX_OFF + (size_t)M_ * 3 * 4;         // M*3 f32
  constexpr size_t W0B_OFF = WTS_OFF + (size_t)M_ * 3 * 4;         // 256*512 bf16
  constexpr size_t W1B_OFF = W0B_OFF + (size_t)C0_ * K2D_ * 2;     // 128*256 bf16
  constexpr size_t XW_OFF  = W1B_OFF + (size_t)C1_ * C0_ * 2;      // B*4*S f32
  constexpr size_t A1_OFF  = XW_OFF + (size_t)B_ * 4 * S_ * 4;     // M*256 bf16
  constexpr size_t A2_OFF  = A1_OFF + (size_t)M_ * C0_ * 2;        // M*128 bf16
  constexpr size_t ST_OFF  = A2_OFF + (size_t)M_ * C1_ * 2;        // 768 f32
  constexpr size_t SS1_OFF = ST_OFF + (size_t)768 * 4;             // 2*256 f32
  constexpr size_t SS2_OFF = SS1_OFF + (size_t)2 * C0_ * 4;        // 2*128 f32

  int*   idx   = (int*)(ws + IDX_OFF);
  float* wts   = (float*)(ws + WTS_OFF);
  short* W0b   = (short*)(ws + W0B_OFF);
  short* W1b   = (short*)(ws + W1B_OFF);
  float* xyz2p = (float*)(ws + XW_OFF);
  short* a1    = (short*)(ws + A1_OFF);
  short* a2    = (short*)(ws + A2_OFF);
  float* st    = (float*)(ws + ST_OFF);   // stats1 = st, stats2 = st + 512
  float* ss1   = (float*)(ws + SS1_OFF);
  float* ss2   = (float*)(ws + SS2_OFF);
  float* outp  = (float*)d_out;

  convw_kernel<<<512, 256, 0, stream>>>(W0, W1, xyz2, W0b, W1b, xyz2p, st);
  topk_kernel<<<B_ * (N_ / 64), 512, 0, stream>>>(xyz1, xyz2p, relw, relb, idx, wts);

  gemm1_kernel<<<M_ / 128, 256, 0, stream>>>(pts1, pts2, idx, wts, W0b, b0, a1, st);
  stats_final_kernel<<<1, 256, 0, stream>>>(st, C0_, b0, g0, be0, ss1);

  gemm2_kernel<<<M_ / 128, 256, 0, stream>>>(a1, W1b, ss1, b1, a2, st + 512);
  stats_final_kernel<<<1, 128, 0, stream>>>(st + 512, C1_, b1, g1, be1, ss2);
  norm2_kernel<<<(size_t)M_ * C1_ / 8 / 256, 256, 0, stream>>>(a2, ss2, outp);
}